// Round 12
// baseline (188.167 us; speedup 1.0000x reference)
//
#include <hip/hip_runtime.h>
#include <cstdint>
#include <cstddef>

#define NCH 128
#define SCAN_CHUNK 2048  // 256 threads x 8 elems
#define GEMM_ROWS 64
#define XPAD 136         // 128 + 8 bf16 pad: A-frag ds_read_b128 conflict-free

typedef short bf16x8 __attribute__((ext_vector_type(8)));
typedef float f32x4 __attribute__((ext_vector_type(4)));
typedef int   i32x2 __attribute__((ext_vector_type(2)));

__device__ __forceinline__ int detect_is64(const unsigned int* __restrict__ ei) {
  // int64 edge_index with ids < 2^31 -> all odd 32-bit words zero. Wave-uniform;
  // call with all lanes active (kernel top, before divergence).
  unsigned int v = ei[((threadIdx.x & 63) << 1) + 1];
  return (__ballot(v != 0u) == 0ULL) ? 1 : 0;
}

__device__ __forceinline__ unsigned short f2bf(float x) {
  unsigned int u = __float_as_uint(x);
  u += 0x7fffu + ((u >> 16) & 1u);  // RNE
  return (unsigned short)(u >> 16);
}

__device__ __forceinline__ int ei_at(const void* ei, long long i, int is64) {
  return is64 ? (int)((const long long*)ei)[i] : ((const int*)ei)[i];
}

// Degree count (1 edge/thread). Emits drank[e] = {d, rank} as one 8 B store so
// the fill pass never re-decodes the strided int64 dst. Blocks >= cbl transpose
// W -> bf16 wt[n][k] (MFMA B operand) under the count's memory time.
__global__ __launch_bounds__(256) void k_count(const void* __restrict__ ei, int E,
                                               int cbl, int* __restrict__ counts,
                                               i32x2* __restrict__ drank,
                                               const float* __restrict__ W,
                                               unsigned short* __restrict__ wt) {
  if ((int)blockIdx.x >= cbl) {
    int idx = (blockIdx.x - cbl) * 256 + threadIdx.x;  // 0..16383
    int n = idx >> 7, k = idx & 127;
    wt[idx] = f2bf(W[k * NCH + n]);
    return;
  }
  int is64 = detect_is64((const unsigned int*)ei);
  int e = blockIdx.x * 256 + threadIdx.x;
  if (e < E) {
    int d = ei_at(ei, (long long)E + e, is64);
    int r = atomicAdd(&counts[d], 1);
    i32x2 dr; dr[0] = d; dr[1] = r;
    __builtin_nontemporal_store(dr, &drank[e]);
  }
}

// Single-pass exclusive scan (decoupled lookback): row_ptr[i+1],
// dis[i] = rsqrt(deg+1).
__global__ __launch_bounds__(256) void k_scan(const int* __restrict__ counts, int N,
                                              unsigned long long* __restrict__ flagsum,
                                              int* __restrict__ row_ptr,
                                              float* __restrict__ dis) {
  int t = threadIdx.x;
  int base = blockIdx.x * SCAN_CHUNK + t * 8;
  int v[8];
  int s = 0;
  if (base + 8 <= N) {
    const int4* p = (const int4*)(counts + base);
    int4 a = p[0], b = p[1];
    v[0] = a.x; v[1] = a.y; v[2] = a.z; v[3] = a.w;
    v[4] = b.x; v[5] = b.y; v[6] = b.z; v[7] = b.w;
  } else {
#pragma unroll
    for (int j = 0; j < 8; ++j) {
      int i = base + j;
      v[j] = (i < N) ? counts[i] : 0;
    }
  }
#pragma unroll
  for (int j = 0; j < 8; ++j) s += v[j];
  int lane = t & 63, w = t >> 6;
  int incl = s;
#pragma unroll
  for (int off = 1; off < 64; off <<= 1) {
    int o = __shfl_up(incl, off);
    if (lane >= off) incl += o;
  }
  __shared__ int wsum[4];
  __shared__ int s_boff;
  if (lane == 63) wsum[w] = incl;
  __syncthreads();
  if (t == 0) {
    int btot = (wsum[0] + wsum[1]) + (wsum[2] + wsum[3]);
    unsigned long long pub = (1ull << 63) | (unsigned int)btot;
    __hip_atomic_store(&flagsum[blockIdx.x], pub, __ATOMIC_RELEASE,
                       __HIP_MEMORY_SCOPE_AGENT);
    int acc = 0;
    for (int i = (int)blockIdx.x - 1; i >= 0; --i) {
      unsigned long long fv;
      do {
        fv = __hip_atomic_load(&flagsum[i], __ATOMIC_ACQUIRE,
                               __HIP_MEMORY_SCOPE_AGENT);
      } while (!(fv >> 63));
      acc += (int)(unsigned int)fv;
    }
    s_boff = acc;
  }
  __syncthreads();
  int woff = 0;
#pragma unroll
  for (int k = 0; k < 4; ++k)
    if (k < w) woff += wsum[k];
  int run = s_boff + woff + (incl - s);
#pragma unroll
  for (int j = 0; j < 8; ++j) {
    run += v[j];
    int i = base + j;
    if (i < N) {
      row_ptr[i + 1] = run;
      dis[i] = rsqrtf((float)(v[j] + 1));  // +1 self-loop; always > 0
    }
  }
  if (blockIdx.x == 0 && t == 0) row_ptr[0] = 0;
}

// Fused: blocks [0,gbl) = MFMA GEMM g[i,:]=bf16(dis[i]*(x@W)); blocks [gbl,..)
// = rank-based CSR fill (no atomics, reads packed drank). MFMA pipe overlaps
// the fill's scatter time.
__global__ __launch_bounds__(256) void k_front(const float* __restrict__ x,
                                               const unsigned short* __restrict__ wt,
                                               const float* __restrict__ dis,
                                               unsigned short* __restrict__ g, int N,
                                               const void* __restrict__ ei, int E,
                                               const i32x2* __restrict__ drank,
                                               const int* __restrict__ row_ptr,
                                               int* __restrict__ edge_src, int gbl) {
  if ((int)blockIdx.x >= gbl) {
    int is64 = detect_is64((const unsigned int*)ei);
    int e = (blockIdx.x - gbl) * 256 + threadIdx.x;
    if (e < E) {
      i32x2 dr = __builtin_nontemporal_load(&drank[e]);
      int s = ei_at(ei, e, is64);
      edge_src[row_ptr[dr[0]] + dr[1]] = s;
    }
    return;
  }
  __shared__ unsigned short xbf[GEMM_ROWS * XPAD];
  __shared__ float sdis[GEMM_ROWS];
  int t = threadIdx.x;
  int row0 = blockIdx.x * GEMM_ROWS;
#pragma unroll
  for (int j = 0; j < 8; ++j) {
    int idx = t + 256 * j;
    int r = idx >> 5, ch = idx & 31;
    int row = row0 + r;
    f32x4 v = {0.f, 0.f, 0.f, 0.f};
    if (row < N)
      v = __builtin_nontemporal_load((const f32x4*)(x + (size_t)row * NCH) + ch);
    ushort4 p;
    p.x = f2bf(v[0]); p.y = f2bf(v[1]); p.z = f2bf(v[2]); p.w = f2bf(v[3]);
    *(ushort4*)&xbf[r * XPAD + ch * 4] = p;
  }
  if (t < GEMM_ROWS) {
    int row = row0 + t;
    sdis[t] = (row < N) ? dis[row] : 0.f;
  }
  int lane = t & 63, wv = t >> 6;
  int n0 = wv * 32, l15 = lane & 15, q = lane >> 4;
  bf16x8 B[4][2];
#pragma unroll
  for (int ks = 0; ks < 4; ++ks)
#pragma unroll
    for (int nt = 0; nt < 2; ++nt) {
      int n = n0 + nt * 16 + l15;
      B[ks][nt] = *(const bf16x8*)(wt + (size_t)n * NCH + ks * 32 + q * 8);
    }
  __syncthreads();
  f32x4 acc[4][2];
#pragma unroll
  for (int mt = 0; mt < 4; ++mt)
#pragma unroll
    for (int nt = 0; nt < 2; ++nt)
#pragma unroll
      for (int i = 0; i < 4; ++i) acc[mt][nt][i] = 0.f;
#pragma unroll
  for (int ks = 0; ks < 4; ++ks) {
#pragma unroll
    for (int mt = 0; mt < 4; ++mt) {
      bf16x8 a = *(const bf16x8*)&xbf[(mt * 16 + l15) * XPAD + ks * 32 + q * 8];
      acc[mt][0] = __builtin_amdgcn_mfma_f32_16x16x32_bf16(a, B[ks][0], acc[mt][0], 0, 0, 0);
      acc[mt][1] = __builtin_amdgcn_mfma_f32_16x16x32_bf16(a, B[ks][1], acc[mt][1], 0, 0, 0);
    }
  }
#pragma unroll
  for (int mt = 0; mt < 4; ++mt) {
#pragma unroll
    for (int reg = 0; reg < 4; ++reg) {
      int rl = mt * 16 + q * 4 + reg;
      int row = row0 + rl;
      if (row < N) {
        float dl = sdis[rl];
        size_t base = (size_t)row * NCH + n0;
        g[base + l15]      = f2bf(acc[mt][0][reg] * dl);
        g[base + 16 + l15] = f2bf(acc[mt][1][reg] * dl);
      }
    }
  }
}

// One wave per node; lane L: half h=L>>5 (edges e+2j+h), sublane sl=L&31 ->
// channels [4sl,4sl+4) as uint2. edge_src read-once -> nontemporal (preserve
// L2 for the x16-reused g).
__global__ __launch_bounds__(256) void k_agg(const unsigned short* __restrict__ g,
                                             const int* __restrict__ row_ptr,
                                             const int* __restrict__ edge_src,
                                             const float* __restrict__ dis,
                                             const float* __restrict__ bias,
                                             float* __restrict__ out, int N) {
  int i = blockIdx.x * 4 + (threadIdx.x >> 6);
  if (i >= N) return;
  int lane = threadIdx.x & 63;
  int h = lane >> 5, sl = lane & 31;
  float a0 = 0.f, a1 = 0.f, a2 = 0.f, a3 = 0.f;
  if (h == 0) {
    uint2 v = *(const uint2*)(g + (size_t)i * NCH + sl * 4);
    a0 = __uint_as_float(v.x << 16);
    a1 = __uint_as_float(v.x & 0xffff0000u);
    a2 = __uint_as_float(v.y << 16);
    a3 = __uint_as_float(v.y & 0xffff0000u);
  }
  int e = row_ptr[i];
  int end = row_ptr[i + 1];
  for (; e + 16 <= end; e += 16) {
    int s[8];
#pragma unroll
    for (int j = 0; j < 8; ++j) s[j] = __builtin_nontemporal_load(&edge_src[e + 2 * j + h]);
    uint2 v[8];
#pragma unroll
    for (int j = 0; j < 8; ++j) v[j] = *(const uint2*)(g + (size_t)s[j] * NCH + sl * 4);
#pragma unroll
    for (int j = 0; j < 8; ++j) {
      a0 += __uint_as_float(v[j].x << 16);
      a1 += __uint_as_float(v[j].x & 0xffff0000u);
      a2 += __uint_as_float(v[j].y << 16);
      a3 += __uint_as_float(v[j].y & 0xffff0000u);
    }
  }
  for (; e + 8 <= end; e += 8) {
    int s[4];
#pragma unroll
    for (int j = 0; j < 4; ++j) s[j] = __builtin_nontemporal_load(&edge_src[e + 2 * j + h]);
    uint2 v[4];
#pragma unroll
    for (int j = 0; j < 4; ++j) v[j] = *(const uint2*)(g + (size_t)s[j] * NCH + sl * 4);
#pragma unroll
    for (int j = 0; j < 4; ++j) {
      a0 += __uint_as_float(v[j].x << 16);
      a1 += __uint_as_float(v[j].x & 0xffff0000u);
      a2 += __uint_as_float(v[j].y << 16);
      a3 += __uint_as_float(v[j].y & 0xffff0000u);
    }
  }
  for (; e < end; e += 2) {
    int idx = e + h;
    if (idx < end) {
      uint2 v = *(const uint2*)(g + (size_t)edge_src[idx] * NCH + sl * 4);
      a0 += __uint_as_float(v.x << 16);
      a1 += __uint_as_float(v.x & 0xffff0000u);
      a2 += __uint_as_float(v.y << 16);
      a3 += __uint_as_float(v.y & 0xffff0000u);
    }
  }
  a0 += __shfl_xor(a0, 32);
  a1 += __shfl_xor(a1, 32);
  a2 += __shfl_xor(a2, 32);
  a3 += __shfl_xor(a3, 32);
  if (h == 0) {
    float di = dis[i];
    float4 bb = ((const float4*)bias)[sl];
    f32x4 o;
    o[0] = fmaxf(fmaf(a0, di, bb.x), 0.f);
    o[1] = fmaxf(fmaf(a1, di, bb.y), 0.f);
    o[2] = fmaxf(fmaf(a2, di, bb.z), 0.f);
    o[3] = fmaxf(fmaf(a3, di, bb.w), 0.f);
    __builtin_nontemporal_store(o, (f32x4*)(out + (size_t)i * NCH + sl * 4));
  }
}

extern "C" void kernel_launch(void* const* d_in, const int* in_sizes, int n_in,
                              void* d_out, int out_size, void* d_ws, size_t ws_size,
                              hipStream_t stream) {
  const float* x    = (const float*)d_in[0];
  const void*  ei   = d_in[1];
  const float* W    = (const float*)d_in[2];
  const float* bias = (const float*)d_in[3];
  float* out = (float*)d_out;

  int N = out_size / NCH;       // 50000
  int E = in_sizes[1] / 2;      // 800000

  char* ws = (char*)d_ws;
  size_t off = 0;
  auto alloc = [&](size_t bytes) -> char* {
    char* p = ws + off;
    off = (off + bytes + 255) & ~(size_t)255;
    return p;
  };
  char* zbase = ws;  // zero region: counts + flagsum (one small memset)
  int*                counts   = (int*)alloc((size_t)N * 4);
  unsigned long long* flagsum  = (unsigned long long*)alloc(1024);
  size_t zbytes = off;
  int*                row_ptr  = (int*)alloc((size_t)(N + 1) * 4);
  float*              dis      = (float*)alloc((size_t)N * 4);
  unsigned short*     wt       = (unsigned short*)alloc((size_t)NCH * NCH * 2);
  i32x2*              drank    = (i32x2*)alloc((size_t)E * 8);
  int*                edge_src = (int*)alloc((size_t)E * 4);
  unsigned short*     g        = (unsigned short*)alloc((size_t)N * NCH * 2);
  (void)ws_size;

  int nb  = (N + SCAN_CHUNK - 1) / SCAN_CHUNK;  // 25
  int gbl = (N + GEMM_ROWS - 1) / GEMM_ROWS;    // 782 gemm blocks
  int cbl = (E + 255) / 256;                    // 3125 count/fill blocks

  (void)hipMemsetAsync(zbase, 0, zbytes, stream);
  k_count<<<cbl + 64, 256, 0, stream>>>(ei, E, cbl, counts, drank, W, wt);
  k_scan<<<nb, 256, 0, stream>>>(counts, N, flagsum, row_ptr, dis);
  k_front<<<gbl + cbl, 256, 0, stream>>>(x, wt, dis, g, N, ei, E, drank, row_ptr,
                                         edge_src, gbl);
  k_agg<<<(N + 3) / 4, 256, 0, stream>>>(g, row_ptr, edge_src, dis, bias, out, N);
}

// Round 13
// 178.129 us; speedup vs baseline: 1.0564x; 1.0564x over previous
//
#include <hip/hip_runtime.h>
#include <cstdint>
#include <cstddef>

#define NCH 128
#define SCAN_CHUNK 2048  // 256 threads x 8 elems
#define GEMM_ROWS 64
#define XPAD 136         // 128 + 8 bf16 pad: A-frag ds_read_b128 conflict-free

typedef short bf16x8 __attribute__((ext_vector_type(8)));
typedef float f32x4 __attribute__((ext_vector_type(4)));

__device__ __forceinline__ int detect_is64(const unsigned int* __restrict__ ei) {
  // int64 edge_index with ids < 2^31 -> all odd 32-bit words zero. Wave-uniform;
  // call with all lanes active (kernel top, before divergence).
  unsigned int v = ei[((threadIdx.x & 63) << 1) + 1];
  return (__ballot(v != 0u) == 0ULL) ? 1 : 0;
}

__device__ __forceinline__ unsigned short f2bf(float x) {
  unsigned int u = __float_as_uint(x);
  u += 0x7fffu + ((u >> 16) & 1u);  // RNE
  return (unsigned short)(u >> 16);
}

__device__ __forceinline__ int ei_at(const void* ei, long long i, int is64) {
  return is64 ? (int)((const long long*)ei)[i] : ((const int*)ei)[i];
}

// Degree count (1 edge/thread, rank kept for atomic-free fill later).
// Blocks >= cbl transpose W -> bf16 wt[n][k] (MFMA B operand), hiding that
// 64-block job under the count's memory time.
__global__ __launch_bounds__(256) void k_count(const void* __restrict__ ei, int E,
                                               int cbl, int* __restrict__ counts,
                                               int* __restrict__ rank,
                                               const float* __restrict__ W,
                                               unsigned short* __restrict__ wt) {
  if ((int)blockIdx.x >= cbl) {
    int idx = (blockIdx.x - cbl) * 256 + threadIdx.x;  // 0..16383
    int n = idx >> 7, k = idx & 127;
    wt[idx] = f2bf(W[k * NCH + n]);
    return;
  }
  int is64 = detect_is64((const unsigned int*)ei);
  int e = blockIdx.x * 256 + threadIdx.x;
  if (e < E) {
    int d = ei_at(ei, (long long)E + e, is64);
    rank[e] = atomicAdd(&counts[d], 1);
  }
}

// Single-pass exclusive scan (decoupled lookback): row_ptr[i+1],
// dis[i] = rsqrt(deg+1).
__global__ __launch_bounds__(256) void k_scan(const int* __restrict__ counts, int N,
                                              unsigned long long* __restrict__ flagsum,
                                              int* __restrict__ row_ptr,
                                              float* __restrict__ dis) {
  int t = threadIdx.x;
  int base = blockIdx.x * SCAN_CHUNK + t * 8;
  int v[8];
  int s = 0;
  if (base + 8 <= N) {
    const int4* p = (const int4*)(counts + base);
    int4 a = p[0], b = p[1];
    v[0] = a.x; v[1] = a.y; v[2] = a.z; v[3] = a.w;
    v[4] = b.x; v[5] = b.y; v[6] = b.z; v[7] = b.w;
  } else {
#pragma unroll
    for (int j = 0; j < 8; ++j) {
      int i = base + j;
      v[j] = (i < N) ? counts[i] : 0;
    }
  }
#pragma unroll
  for (int j = 0; j < 8; ++j) s += v[j];
  int lane = t & 63, w = t >> 6;
  int incl = s;
#pragma unroll
  for (int off = 1; off < 64; off <<= 1) {
    int o = __shfl_up(incl, off);
    if (lane >= off) incl += o;
  }
  __shared__ int wsum[4];
  __shared__ int s_boff;
  if (lane == 63) wsum[w] = incl;
  __syncthreads();
  if (t == 0) {
    int btot = (wsum[0] + wsum[1]) + (wsum[2] + wsum[3]);
    unsigned long long pub = (1ull << 63) | (unsigned int)btot;
    __hip_atomic_store(&flagsum[blockIdx.x], pub, __ATOMIC_RELEASE,
                       __HIP_MEMORY_SCOPE_AGENT);
    int acc = 0;
    for (int i = (int)blockIdx.x - 1; i >= 0; --i) {
      unsigned long long fv;
      do {
        fv = __hip_atomic_load(&flagsum[i], __ATOMIC_ACQUIRE,
                               __HIP_MEMORY_SCOPE_AGENT);
      } while (!(fv >> 63));
      acc += (int)(unsigned int)fv;
    }
    s_boff = acc;
  }
  __syncthreads();
  int woff = 0;
#pragma unroll
  for (int k = 0; k < 4; ++k)
    if (k < w) woff += wsum[k];
  int run = s_boff + woff + (incl - s);
#pragma unroll
  for (int j = 0; j < 8; ++j) {
    run += v[j];
    int i = base + j;
    if (i < N) {
      row_ptr[i + 1] = run;
      dis[i] = rsqrtf((float)(v[j] + 1));  // +1 self-loop; always > 0
    }
  }
  if (blockIdx.x == 0 && t == 0) row_ptr[0] = 0;
}

// Fused: blocks [0,gbl) = MFMA GEMM g[i,:]=bf16(dis[i]*(x@W)); blocks [gbl,..)
// = rank-based CSR fill (no atomics). MFMA pipe overlaps fill's scatter time.
__global__ __launch_bounds__(256) void k_front(const float* __restrict__ x,
                                               const unsigned short* __restrict__ wt,
                                               const float* __restrict__ dis,
                                               unsigned short* __restrict__ g, int N,
                                               const void* __restrict__ ei, int E,
                                               const int* __restrict__ rank,
                                               const int* __restrict__ row_ptr,
                                               int* __restrict__ edge_src, int gbl) {
  if ((int)blockIdx.x >= gbl) {
    int is64 = detect_is64((const unsigned int*)ei);
    int e = (blockIdx.x - gbl) * 256 + threadIdx.x;
    if (e < E) {
      int s = ei_at(ei, e, is64);
      int d = ei_at(ei, (long long)E + e, is64);
      edge_src[row_ptr[d] + rank[e]] = s;
    }
    return;
  }
  __shared__ unsigned short xbf[GEMM_ROWS * XPAD];
  __shared__ float sdis[GEMM_ROWS];
  int t = threadIdx.x;
  int row0 = blockIdx.x * GEMM_ROWS;
#pragma unroll
  for (int j = 0; j < 8; ++j) {
    int idx = t + 256 * j;
    int r = idx >> 5, ch = idx & 31;
    int row = row0 + r;
    float4 v = (row < N) ? ((const float4*)(x + (size_t)row * NCH))[ch]
                         : make_float4(0.f, 0.f, 0.f, 0.f);
    ushort4 p;
    p.x = f2bf(v.x); p.y = f2bf(v.y); p.z = f2bf(v.z); p.w = f2bf(v.w);
    *(ushort4*)&xbf[r * XPAD + ch * 4] = p;
  }
  if (t < GEMM_ROWS) {
    int row = row0 + t;
    sdis[t] = (row < N) ? dis[row] : 0.f;
  }
  int lane = t & 63, wv = t >> 6;
  int n0 = wv * 32, l15 = lane & 15, q = lane >> 4;
  bf16x8 B[4][2];
#pragma unroll
  for (int ks = 0; ks < 4; ++ks)
#pragma unroll
    for (int nt = 0; nt < 2; ++nt) {
      int n = n0 + nt * 16 + l15;
      B[ks][nt] = *(const bf16x8*)(wt + (size_t)n * NCH + ks * 32 + q * 8);
    }
  __syncthreads();
  f32x4 acc[4][2];
#pragma unroll
  for (int mt = 0; mt < 4; ++mt)
#pragma unroll
    for (int nt = 0; nt < 2; ++nt)
#pragma unroll
      for (int i = 0; i < 4; ++i) acc[mt][nt][i] = 0.f;
#pragma unroll
  for (int ks = 0; ks < 4; ++ks) {
#pragma unroll
    for (int mt = 0; mt < 4; ++mt) {
      bf16x8 a = *(const bf16x8*)&xbf[(mt * 16 + l15) * XPAD + ks * 32 + q * 8];
      acc[mt][0] = __builtin_amdgcn_mfma_f32_16x16x32_bf16(a, B[ks][0], acc[mt][0], 0, 0, 0);
      acc[mt][1] = __builtin_amdgcn_mfma_f32_16x16x32_bf16(a, B[ks][1], acc[mt][1], 0, 0, 0);
    }
  }
#pragma unroll
  for (int mt = 0; mt < 4; ++mt) {
#pragma unroll
    for (int reg = 0; reg < 4; ++reg) {
      int rl = mt * 16 + q * 4 + reg;
      int row = row0 + rl;
      if (row < N) {
        float dl = sdis[rl];
        size_t base = (size_t)row * NCH + n0;
        g[base + l15]      = f2bf(acc[mt][0][reg] * dl);
        g[base + 16 + l15] = f2bf(acc[mt][1][reg] * dl);
      }
    }
  }
}

// One wave per node; lane L: half h=L>>5 (edges e+2j+h), sublane sl=L&31 ->
// channels [4sl,4sl+4) as uint2. 16-edge main loop (8 g-loads in flight/half).
__global__ __launch_bounds__(256) void k_agg(const unsigned short* __restrict__ g,
                                             const int* __restrict__ row_ptr,
                                             const int* __restrict__ edge_src,
                                             const float* __restrict__ dis,
                                             const float* __restrict__ bias,
                                             float* __restrict__ out, int N) {
  int i = blockIdx.x * 4 + (threadIdx.x >> 6);
  if (i >= N) return;
  int lane = threadIdx.x & 63;
  int h = lane >> 5, sl = lane & 31;
  float a0 = 0.f, a1 = 0.f, a2 = 0.f, a3 = 0.f;
  if (h == 0) {
    uint2 v = *(const uint2*)(g + (size_t)i * NCH + sl * 4);
    a0 = __uint_as_float(v.x << 16);
    a1 = __uint_as_float(v.x & 0xffff0000u);
    a2 = __uint_as_float(v.y << 16);
    a3 = __uint_as_float(v.y & 0xffff0000u);
  }
  int e = row_ptr[i];
  int end = row_ptr[i + 1];
  for (; e + 16 <= end; e += 16) {
    int s[8];
#pragma unroll
    for (int j = 0; j < 8; ++j) s[j] = edge_src[e + 2 * j + h];
    uint2 v[8];
#pragma unroll
    for (int j = 0; j < 8; ++j) v[j] = *(const uint2*)(g + (size_t)s[j] * NCH + sl * 4);
#pragma unroll
    for (int j = 0; j < 8; ++j) {
      a0 += __uint_as_float(v[j].x << 16);
      a1 += __uint_as_float(v[j].x & 0xffff0000u);
      a2 += __uint_as_float(v[j].y << 16);
      a3 += __uint_as_float(v[j].y & 0xffff0000u);
    }
  }
  for (; e + 8 <= end; e += 8) {
    int s[4];
#pragma unroll
    for (int j = 0; j < 4; ++j) s[j] = edge_src[e + 2 * j + h];
    uint2 v[4];
#pragma unroll
    for (int j = 0; j < 4; ++j) v[j] = *(const uint2*)(g + (size_t)s[j] * NCH + sl * 4);
#pragma unroll
    for (int j = 0; j < 4; ++j) {
      a0 += __uint_as_float(v[j].x << 16);
      a1 += __uint_as_float(v[j].x & 0xffff0000u);
      a2 += __uint_as_float(v[j].y << 16);
      a3 += __uint_as_float(v[j].y & 0xffff0000u);
    }
  }
  for (; e < end; e += 2) {
    int idx = e + h;
    if (idx < end) {
      uint2 v = *(const uint2*)(g + (size_t)edge_src[idx] * NCH + sl * 4);
      a0 += __uint_as_float(v.x << 16);
      a1 += __uint_as_float(v.x & 0xffff0000u);
      a2 += __uint_as_float(v.y << 16);
      a3 += __uint_as_float(v.y & 0xffff0000u);
    }
  }
  a0 += __shfl_xor(a0, 32);
  a1 += __shfl_xor(a1, 32);
  a2 += __shfl_xor(a2, 32);
  a3 += __shfl_xor(a3, 32);
  if (h == 0) {
    float di = dis[i];
    float4 bb = ((const float4*)bias)[sl];
    f32x4 o;
    o[0] = fmaxf(fmaf(a0, di, bb.x), 0.f);
    o[1] = fmaxf(fmaf(a1, di, bb.y), 0.f);
    o[2] = fmaxf(fmaf(a2, di, bb.z), 0.f);
    o[3] = fmaxf(fmaf(a3, di, bb.w), 0.f);
    __builtin_nontemporal_store(o, (f32x4*)(out + (size_t)i * NCH + sl * 4));
  }
}

extern "C" void kernel_launch(void* const* d_in, const int* in_sizes, int n_in,
                              void* d_out, int out_size, void* d_ws, size_t ws_size,
                              hipStream_t stream) {
  const float* x    = (const float*)d_in[0];
  const void*  ei   = d_in[1];
  const float* W    = (const float*)d_in[2];
  const float* bias = (const float*)d_in[3];
  float* out = (float*)d_out;

  int N = out_size / NCH;       // 50000
  int E = in_sizes[1] / 2;      // 800000

  char* ws = (char*)d_ws;
  size_t off = 0;
  auto alloc = [&](size_t bytes) -> char* {
    char* p = ws + off;
    off = (off + bytes + 255) & ~(size_t)255;
    return p;
  };
  char* zbase = ws;  // zero region: counts + flagsum (one small memset)
  int*                counts   = (int*)alloc((size_t)N * 4);
  unsigned long long* flagsum  = (unsigned long long*)alloc(1024);
  size_t zbytes = off;
  int*                row_ptr  = (int*)alloc((size_t)(N + 1) * 4);
  float*              dis      = (float*)alloc((size_t)N * 4);
  unsigned short*     wt       = (unsigned short*)alloc((size_t)NCH * NCH * 2);
  int*                rank     = (int*)alloc((size_t)E * 4);
  int*                edge_src = (int*)alloc((size_t)E * 4);
  unsigned short*     g        = (unsigned short*)alloc((size_t)N * NCH * 2);
  (void)ws_size;

  int nb  = (N + SCAN_CHUNK - 1) / SCAN_CHUNK;  // 25
  int gbl = (N + GEMM_ROWS - 1) / GEMM_ROWS;    // 782 gemm blocks
  int cbl = (E + 255) / 256;                    // 3125 count/fill blocks

  (void)hipMemsetAsync(zbase, 0, zbytes, stream);
  k_count<<<cbl + 64, 256, 0, stream>>>(ei, E, cbl, counts, rank, W, wt);
  k_scan<<<nb, 256, 0, stream>>>(counts, N, flagsum, row_ptr, dis);
  k_front<<<gbl + cbl, 256, 0, stream>>>(x, wt, dis, g, N, ei, E, rank, row_ptr,
                                         edge_src, gbl);
  k_agg<<<(N + 3) / 4, 256, 0, stream>>>(g, row_ptr, edge_src, dis, bias, out, N);
}